// Round 11
// baseline (188.333 us; speedup 1.0000x reference)
//
#include <hip/hip_runtime.h>

// MLSA-style multi-stage time-varying FIR.
// y = (sum_{n=0..20} F^n x / n!) * exp(lerp(mc[...,0]))
// F: xn[t] = sum_{d=1..49} lerp_t(mc[:, :, d]) * xa[t-d]
//
// Round-10: R2's balanced shape (NT=768 -> 12 waves, 3/SIMD on every SIMD;
// VALU critical path 4848 cyc/stage = 40us floor) + R7's named-register taps
// + the occupancy knob PROVEN in R9/R10: amdgpu_waves_per_eu. R2-R9's NT=768
// builds were pinned at 84 VGPR (6 waves/EU assumption) which spilled any
// tap cache; amdgpu_waves_per_eu(3,3) raises the budget to 512/3 ~ 170.
// Taps for lags 1..36 in 18 NAMED float4s (~72 VGPR, demand ~155); lags
// 37..49 from LDS (7 float4/stage). Per-thread LDS/stage: 40 -> 22 ops.

#define FO    49      // filter order (lags 1..49)
#define FP    80      // frame period
#define NST   20      // Taylor stages
#define NB    8       // batch
#define TT    160000  // samples per batch row
#define NFR   2000    // frames
#define NC    50      // coeffs per frame
#define HALO  1024    // left halo (>= 20*49=980)
#define NT    768     // threads per block (12 waves; 3 per SIMD, balanced)
#define RPT   8       // samples per thread (8 | 80 -> thread stays in 1 frame)
#define EE    6144    // NT*RPT extended region
#define TOUT  5120    // EE - HALO outputs per tile
#define TILES 32      // TT / TOUT coverage (32*5120 = 163840 >= 160000)
#define PADW  56      // zero pad words in front of data (underrun reach: 52)
#define NFRL  78      // tap rows per block
#define TROW  100     // tap row stride in words (49 float2 + pad; 400B)

// 16B-group XOR swizzle. NOTE: swz(g+1) != swz(g)+1 in odd octets -- always
// swizzle each group address individually (round-3 bug).
__device__ __forceinline__ int swz(int g) { return g ^ ((g >> 3) & 7); }

// One tap pair (lags d0=2*PP+1, d1=2*PP+2) applied to all RPT samples.
// PP must be a compile-time literal; branches fold under unroll.
#define TAPSTEP(PP, TP)                                                \
  {                                                                    \
    const int d0 = 2 * (PP) + 1, d1 = 2 * (PP) + 2;                    \
    _Pragma("unroll")                                                  \
    for (int j = 0; j < RPT; ++j) {                                    \
      const int ka = 52 + j - d0;                                      \
      const float va = (ka < 52) ? A[ka] : xp[ka - 52];                \
      acc0[j] = fmaf((TP).x, va, acc0[j]);                             \
      acc1[j] = fmaf((TP).y, va, acc1[j]);                             \
      if (d1 <= FO) {                                                  \
        const int kb = 52 + j - d1;                                    \
        const float vb = (kb < 52) ? A[kb] : xp[kb - 52];              \
        acc0[j] = fmaf((TP).z, vb, acc0[j]);                           \
        acc1[j] = fmaf((TP).w, vb, acc1[j]);                           \
      }                                                                \
    }                                                                  \
  }

__global__ __launch_bounds__(NT)
__attribute__((amdgpu_waves_per_eu(3, 3)))
void mlsa_kernel(
    const float* __restrict__ x, const float* __restrict__ mc,
    float* __restrict__ out) {
  __shared__ __align__(16) float sb0[PADW + EE];
  __shared__ __align__(16) float sb1[PADW + EE];
  __shared__ __align__(16) float taps[NFRL * TROW];

  const int tid  = threadIdx.x;
  const int b    = blockIdx.x >> 5;   // TILES == 32
  const int tile = blockIdx.x & 31;
  const int base = tile * TOUT - HALO;  // global sample index of local 0
  const float* __restrict__ xb  = x + b * TT;
  const float* __restrict__ mcb = mc + b * NFR * NC;

  if (tid < PADW) { sb0[tid] = 0.f; sb1[tid] = 0.f; }

  // Stage x tile into sb0 (stride-1 groups, coalesced; base%4==0, TT%4==0).
  #pragma unroll
  for (int i = 0; i < EE / 4 / NT; ++i) {
    const int q  = i * NT + tid;
    const int t0 = base + q * 4;
    float4 v = make_float4(0.f, 0.f, 0.f, 0.f);
    if (t0 >= 0 && t0 < TT) v = *(const float4*)(xb + t0);
    *(float4*)(sb0 + PADW + 4 * swz(q)) = v;
  }

  // Tap table -> LDS. Row e = frame fb+e; word 2*(d-1) = {c_d, dc_d/FP}.
  const int fb = max(base, 0) / FP;
  for (int idx = tid; idx < NFRL * FO; idx += NT) {
    const int e  = idx / FO;
    const int dm = idx - e * FO;
    const int fa = min(fb + e, NFR - 1);
    const int fn = min(fb + e + 1, NFR - 1);
    const float a0 = mcb[fa * NC + dm + 1];
    const float a1 = mcb[fn * NC + dm + 1];
    *(float2*)(taps + e * TROW + 2 * dm) = make_float2(a0, (a1 - a0) * (1.0f / FP));
  }

  // Flat map: thread owns samples 8*tid .. 8*tid+7 (one frame: 8|80).
  const int g0 = base + RPT * tid;
  const int gc = min(max(g0, 0), TT - 1);
  const int n0 = gc / FP;
  const int fi = n0 - fb;
  const float p0f = (float)(gc - n0 * FP);

  // Window LDS group addresses (each swizzled individually): groups
  // 2*tid-13 .. 2*tid-1 cover words 8*tid-52 .. 8*tid-1; q<0 -> pad region.
  int widx[13];
  #pragma unroll
  for (int i = 0; i < 13; ++i) {
    const int q = 2 * tid - 13 + i;
    widx[i] = (q < 0) ? (PADW + 4 * q) : (PADW + 4 * swz(q));
  }
  const int sidx0 = PADW + 4 * swz(2 * tid);
  const int sidx1 = PADW + 4 * swz(2 * tid + 1);

  // Own 8 samples; xp persists across stages (= prev stage values).
  float xp[RPT];
  #pragma unroll
  for (int k = 0; k < 2; ++k) {
    const int t0 = g0 + 4 * k;
    float4 v = make_float4(0.f, 0.f, 0.f, 0.f);
    if (t0 >= 0 && t0 < TT) v = *(const float4*)(xb + t0);
    xp[4*k] = v.x; xp[4*k+1] = v.y; xp[4*k+2] = v.z; xp[4*k+3] = v.w;
  }
  float y[RPT];
  #pragma unroll
  for (int j = 0; j < RPT; ++j) y[j] = xp[j];

  __syncthreads();

  // Taps for lags 1..36 in 18 NAMED float4s (VGPR budget 170 via
  // waves_per_eu(3,3); demand ~155).
  const float* trow = taps + fi * TROW;
  const float4 t00 = *(const float4*)(trow +  0);
  const float4 t01 = *(const float4*)(trow +  4);
  const float4 t02 = *(const float4*)(trow +  8);
  const float4 t03 = *(const float4*)(trow + 12);
  const float4 t04 = *(const float4*)(trow + 16);
  const float4 t05 = *(const float4*)(trow + 20);
  const float4 t06 = *(const float4*)(trow + 24);
  const float4 t07 = *(const float4*)(trow + 28);
  const float4 t08 = *(const float4*)(trow + 32);
  const float4 t09 = *(const float4*)(trow + 36);
  const float4 t10 = *(const float4*)(trow + 40);
  const float4 t11 = *(const float4*)(trow + 44);
  const float4 t12 = *(const float4*)(trow + 48);
  const float4 t13 = *(const float4*)(trow + 52);
  const float4 t14 = *(const float4*)(trow + 56);
  const float4 t15 = *(const float4*)(trow + 60);
  const float4 t16 = *(const float4*)(trow + 64);
  const float4 t17 = *(const float4*)(trow + 68);

  const float* rb = sb0;
  float*       wb = sb1;
  #pragma unroll 1
  for (int s = 1; s <= NST; ++s) {
    // A[m] = stage-(s-1) value at word 8*tid-52+m, m = 0..51; own 8 in xp.
    float A[52];
    #pragma unroll
    for (int i = 0; i < 13; ++i) {
      const float4 v = *(const float4*)(rb + widx[i]);
      A[4*i] = v.x; A[4*i+1] = v.y; A[4*i+2] = v.z; A[4*i+3] = v.w;
    }
    float acc0[RPT], acc1[RPT];
    #pragma unroll
    for (int j = 0; j < RPT; ++j) { acc0[j] = 0.f; acc1[j] = 0.f; }
    // Lags 1..36 from named register taps.
    TAPSTEP(0,  t00) TAPSTEP(1,  t01) TAPSTEP(2,  t02) TAPSTEP(3,  t03)
    TAPSTEP(4,  t04) TAPSTEP(5,  t05) TAPSTEP(6,  t06) TAPSTEP(7,  t07)
    TAPSTEP(8,  t08) TAPSTEP(9,  t09) TAPSTEP(10, t10) TAPSTEP(11, t11)
    TAPSTEP(12, t12) TAPSTEP(13, t13) TAPSTEP(14, t14) TAPSTEP(15, t15)
    TAPSTEP(16, t16) TAPSTEP(17, t17)
    // Lags 37..49 from LDS (p compile-time under unroll; d1=50 slot dummy).
    #pragma unroll
    for (int p = 18; p < 25; ++p) {
      const float4 tp = *(const float4*)(trow + 4 * p);
      TAPSTEP(p, tp)
    }
    const float ia = 1.0f / (float)s;
    #pragma unroll
    for (int j = 0; j < RPT; ++j) {
      const float xn = fmaf(p0f + (float)j, acc1[j], acc0[j]) * ia;
      y[j] += xn;
      xp[j] = xn;
    }
    {
      float4 v;
      v.x = xp[0]; v.y = xp[1]; v.z = xp[2]; v.w = xp[3];
      *(float4*)(wb + sidx0) = v;
      v.x = xp[4]; v.y = xp[5]; v.z = xp[6]; v.w = xp[7];
      *(float4*)(wb + sidx1) = v;
    }
    __syncthreads();
    const float* t = rb; rb = wb; wb = (float*)t;
  }

  // Epilogue: out = y * exp(lerp(mc[...,0])). Outputs are samples >= HALO.
  if (tid >= HALO / RPT && g0 < TT) {
    const int n1 = min(n0 + 1, NFR - 1);
    const float k0 = mcb[n0 * NC];
    const float k1 = mcb[n1 * NC];
    const float dk = (k1 - k0) * (1.0f / FP);
    float* ob = out + b * TT + g0;
    #pragma unroll
    for (int k = 0; k < 2; ++k) {
      float4 v;
      #pragma unroll
      for (int e = 0; e < 4; ++e) {
        const int j = 4 * k + e;
        const float Kg = __expf(fmaf(p0f + (float)j, dk, k0));
        ((float*)&v)[e] = y[j] * Kg;
      }
      *(float4*)(ob + 4 * k) = v;
    }
  }
}

extern "C" void kernel_launch(void* const* d_in, const int* in_sizes, int n_in,
                              void* d_out, int out_size, void* d_ws, size_t ws_size,
                              hipStream_t stream) {
  const float* x  = (const float*)d_in[0];
  const float* mc = (const float*)d_in[1];
  float* out      = (float*)d_out;
  mlsa_kernel<<<NB * TILES, NT, 0, stream>>>(x, mc, out);
}